// Round 2
// baseline (6170.308 us; speedup 1.0000x reference)
//
#include <hip/hip_runtime.h>

// ---------------------------------------------------------------------------
// Fused MANN. R1 change vs R0: ROWS 64->32 so LDS 99KB->50.7KB -> 3 blocks/CU
// (12 waves/CU, 3 waves/SIMD) to fix the latency-bound 18% VALUBusy seen in
// rocprof. Structure otherwise identical (blend folded into x operand, LN via
// 16-lane shfl reductions, weights streamed from L2).
// ---------------------------------------------------------------------------

constexpr int B_TOT = 131072;
constexpr int IN    = 256;
constexpr int HID   = 128;
constexpr int GH    = 64;
constexpr int KEXP  = 4;
constexpr int NA    = 3;
constexpr int ROWS  = 32;        // rows per block (R1: was 64)
constexpr int RPT   = 2;         // rows per thread
constexpr int XS    = IN + 4;    // padded stride for x tile (floats)
constexpr int YS    = HID + 4;   // padded stride for hidden tiles
constexpr int HS    = GH + 4;    // padded stride for gating hidden
constexpr float EPS = 1e-5f;

// Blended expert layer: sout[r][o] = relu(LN_o( sum_k bl[r][k] *
//   (dot(sin[r], W[k][o]) + eb[k][o]) ))
template<int L, int SIN>
__device__ __forceinline__ void expert_layer(
    const float* sin_, float* sout,
    const float bl[RPT][4], int r0, int og,
    const float* __restrict__ W, const float* __restrict__ eb,
    const float* __restrict__ lg, const float* __restrict__ lb)
{
  float acc[RPT][8];
#pragma unroll
  for (int r = 0; r < RPT; ++r)
#pragma unroll
    for (int j = 0; j < 8; ++j) acc[r][j] = 0.f;

  for (int ic = 0; ic < L / 4; ++ic) {
    float4 xv[RPT];
#pragma unroll
    for (int r = 0; r < RPT; ++r)
      xv[r] = *(const float4*)&sin_[(r0 + r) * SIN + ic * 4];
#pragma unroll
    for (int k = 0; k < KEXP; ++k) {
      float4 tx[RPT];
#pragma unroll
      for (int r = 0; r < RPT; ++r) {
        const float s = bl[r][k];
        tx[r].x = s * xv[r].x; tx[r].y = s * xv[r].y;
        tx[r].z = s * xv[r].z; tx[r].w = s * xv[r].w;
      }
#pragma unroll
      for (int j = 0; j < 8; ++j) {
        const float4 wv =
            *(const float4*)&W[((size_t)(k * HID + og * 8 + j)) * L + ic * 4];
#pragma unroll
        for (int r = 0; r < RPT; ++r)
          acc[r][j] = fmaf(tx[r].x, wv.x,
                      fmaf(tx[r].y, wv.y,
                      fmaf(tx[r].z, wv.z,
                      fmaf(tx[r].w, wv.w, acc[r][j]))));
      }
    }
  }

  // blended bias
#pragma unroll
  for (int j = 0; j < 8; ++j) {
    const int o = og * 8 + j;
#pragma unroll
    for (int k = 0; k < KEXP; ++k) {
      const float ebv = eb[k * HID + o];
#pragma unroll
      for (int r = 0; r < RPT; ++r) acc[r][j] += bl[r][k] * ebv;
    }
  }

  // LayerNorm over 128 outs (8 per thread x 16 og-lanes) + relu + store
#pragma unroll
  for (int r = 0; r < RPT; ++r) {
    float s = 0.f;
#pragma unroll
    for (int j = 0; j < 8; ++j) s += acc[r][j];
#pragma unroll
    for (int m = 1; m < 16; m <<= 1) s += __shfl_xor(s, m, 64);
    const float mu = s * (1.0f / 128.0f);
    float q = 0.f;
#pragma unroll
    for (int j = 0; j < 8; ++j) { const float d = acc[r][j] - mu; q += d * d; }
#pragma unroll
    for (int m = 1; m < 16; m <<= 1) q += __shfl_xor(q, m, 64);
    const float rstd = rsqrtf(q * (1.0f / 128.0f) + EPS);
#pragma unroll
    for (int j = 0; j < 8; ++j) {
      const int o = og * 8 + j;
      const float y = (acc[r][j] - mu) * rstd * lg[o] + lb[o];
      sout[(r0 + r) * YS + o] = fmaxf(y, 0.f);
    }
  }
}

__global__ __launch_bounds__(256, 3) void mann_fused(
    const float* __restrict__ state,
    const float* __restrict__ gw1, const float* __restrict__ gb1,
    const float* __restrict__ gln_g, const float* __restrict__ gln_b,
    const float* __restrict__ gw2, const float* __restrict__ gb2,
    const float* __restrict__ temperature,
    const float* __restrict__ e1_w, const float* __restrict__ e1_b,
    const float* __restrict__ ln1_g, const float* __restrict__ ln1_b,
    const float* __restrict__ e2_w, const float* __restrict__ e2_b,
    const float* __restrict__ ln2_g, const float* __restrict__ ln2_b,
    const float* __restrict__ e3_w, const float* __restrict__ e3_b,
    float* __restrict__ out_policy, float* __restrict__ out_blend)
{
  // LDS: x tile (32x260) | a tile (32x132, doubles as gating-h 32x68) | blend
  // b tile overlays the x tile (x is dead after layer 1). Total 50688 B.
  __shared__ float smem[ROWS * XS + ROWS * YS + ROWS * KEXP];
  float* sx  = smem;
  float* sa  = smem + ROWS * XS;
  float* sb  = smem;                       // overlay: valid after layer-1 sync
  float* sh  = sa;                         // gating hidden, stride HS
  float* sbl = smem + ROWS * XS + ROWS * YS;

  const int tid = threadIdx.x;
  const int rowbase = blockIdx.x * ROWS;
  const int rowg = tid >> 4, og = tid & 15;
  const int r0 = rowg * RPT;

  // ---- Phase A: stage 32x256 fp32 x-tile (fully coalesced float4) ----
  {
    const float4* gsrc =
        reinterpret_cast<const float4*>(state + (size_t)rowbase * IN);
#pragma unroll
    for (int it = 0; it < 8; ++it) {
      const int fi = tid + it * 256;        // 0..2047
      const int row = fi >> 6, c4 = fi & 63;
      const float4 v = gsrc[fi];
      *reinterpret_cast<float4*>(&sx[row * XS + c4 * 4]) = v;
    }
  }
  __syncthreads();

  // ---- Phase B: gating hidden (256 -> 64) + LN + relu ----
  {
    float acc[RPT][4];
#pragma unroll
    for (int r = 0; r < RPT; ++r)
#pragma unroll
      for (int j = 0; j < 4; ++j) acc[r][j] = 0.f;

    for (int ic = 0; ic < IN / 4; ++ic) {
      float4 xv[RPT];
#pragma unroll
      for (int r = 0; r < RPT; ++r)
        xv[r] = *(const float4*)&sx[(r0 + r) * XS + ic * 4];
#pragma unroll
      for (int j = 0; j < 4; ++j) {
        const float4 wv = *(const float4*)&gw1[(og * 4 + j) * IN + ic * 4];
#pragma unroll
        for (int r = 0; r < RPT; ++r)
          acc[r][j] = fmaf(xv[r].x, wv.x,
                      fmaf(xv[r].y, wv.y,
                      fmaf(xv[r].z, wv.z,
                      fmaf(xv[r].w, wv.w, acc[r][j]))));
      }
    }

    // +bias, LN over 64, relu, store h
#pragma unroll
    for (int r = 0; r < RPT; ++r) {
      float v[4];
      float s = 0.f;
#pragma unroll
      for (int j = 0; j < 4; ++j) {
        v[j] = acc[r][j] + gb1[og * 4 + j];
        s += v[j];
      }
#pragma unroll
      for (int m = 1; m < 16; m <<= 1) s += __shfl_xor(s, m, 64);
      const float mu = s * (1.0f / 64.0f);
      float q = 0.f;
#pragma unroll
      for (int j = 0; j < 4; ++j) { const float d = v[j] - mu; q += d * d; }
#pragma unroll
      for (int m = 1; m < 16; m <<= 1) q += __shfl_xor(q, m, 64);
      const float rstd = rsqrtf(q * (1.0f / 64.0f) + EPS);
#pragma unroll
      for (int j = 0; j < 4; ++j) {
        const int o = og * 4 + j;
        const float hh = (v[j] - mu) * rstd * gln_g[o] + gln_b[o];
        sh[(r0 + r) * HS + o] = fmaxf(hh, 0.f);
      }
    }
  }
  __syncthreads();

  // ---- Phase B2: logits + softmax -> blend (128 threads: 32 rows x 4 k) ----
  if (tid < ROWS * KEXP) {
    const int row = tid >> 2, k = tid & 3;
    float s = 0.f;
    for (int i = 0; i < GH; ++i) s += sh[row * HS + i] * gw2[k * GH + i];
    s += gb2[k];
    float t = temperature[0];
    t = fminf(fmaxf(t, 0.1f), 2.0f);
    s = s / t;
    float m = s;
    m = fmaxf(m, __shfl_xor(m, 1, 64));
    m = fmaxf(m, __shfl_xor(m, 2, 64));
    const float e = expf(s - m);
    float sum = e;
    sum += __shfl_xor(sum, 1, 64);
    sum += __shfl_xor(sum, 2, 64);
    const float bl = e / sum;
    sbl[row * 4 + k] = bl;
    out_blend[(size_t)(rowbase + row) * 4 + k] = bl;
  }
  __syncthreads();

  // blends for my rows into registers
  float bl[RPT][4];
#pragma unroll
  for (int r = 0; r < RPT; ++r)
#pragma unroll
    for (int k = 0; k < 4; ++k) bl[r][k] = sbl[(r0 + r) * 4 + k];

  // ---- Phase C: expert layer 1 (256 -> 128), writes sa ----
  expert_layer<IN, XS>(sx, sa, bl, r0, og, e1_w, e1_b, ln1_g, ln1_b);
  __syncthreads();

  // ---- Phase D: expert layer 2 (128 -> 128), writes sb (overlays sx) ----
  expert_layer<HID, YS>(sa, sb, bl, r0, og, e2_w, e2_b, ln2_g, ln2_b);
  __syncthreads();

  // ---- Phase E: expert layer 3 (128 -> 3) + blend reduce ----
  if (tid < ROWS * KEXP) {
    const int row = tid >> 2, k = tid & 3;
    float p[NA] = {0.f, 0.f, 0.f};
    for (int ic = 0; ic < HID / 4; ++ic) {
      const float4 xv = *(const float4*)&sb[row * YS + ic * 4];
#pragma unroll
      for (int a = 0; a < NA; ++a) {
        const float4 wv =
            *(const float4*)&e3_w[((size_t)(k * NA + a)) * HID + ic * 4];
        p[a] = fmaf(xv.x, wv.x,
               fmaf(xv.y, wv.y,
               fmaf(xv.z, wv.z,
               fmaf(xv.w, wv.w, p[a]))));
      }
    }
    const float blk = sbl[row * 4 + k];
#pragma unroll
    for (int a = 0; a < NA; ++a) p[a] = blk * (p[a] + e3_b[k * NA + a]);
#pragma unroll
    for (int a = 0; a < NA; ++a) {
      p[a] += __shfl_xor(p[a], 1, 64);
      p[a] += __shfl_xor(p[a], 2, 64);
    }
    if (k == 0) {
      const size_t o = (size_t)(rowbase + row) * NA;
      out_policy[o + 0] = p[0];
      out_policy[o + 1] = p[1];
      out_policy[o + 2] = p[2];
    }
  }
}

extern "C" void kernel_launch(void* const* d_in, const int* in_sizes, int n_in,
                              void* d_out, int out_size, void* d_ws, size_t ws_size,
                              hipStream_t stream) {
  const float* state = (const float*)d_in[0];
  const float* gw1   = (const float*)d_in[1];
  const float* gb1   = (const float*)d_in[2];
  const float* gln_g = (const float*)d_in[3];
  const float* gln_b = (const float*)d_in[4];
  const float* gw2   = (const float*)d_in[5];
  const float* gb2   = (const float*)d_in[6];
  const float* temp  = (const float*)d_in[7];
  const float* e1_w  = (const float*)d_in[8];
  const float* e1_b  = (const float*)d_in[9];
  const float* ln1_g = (const float*)d_in[10];
  const float* ln1_b = (const float*)d_in[11];
  const float* e2_w  = (const float*)d_in[12];
  const float* e2_b  = (const float*)d_in[13];
  const float* ln2_g = (const float*)d_in[14];
  const float* ln2_b = (const float*)d_in[15];
  const float* e3_w  = (const float*)d_in[16];
  const float* e3_b  = (const float*)d_in[17];

  float* out_policy = (float*)d_out;                       // [B,3]
  float* out_blend  = (float*)d_out + (size_t)B_TOT * NA;  // [B,4]

  const int grid = B_TOT / ROWS;  // 4096
  mann_fused<<<grid, 256, 0, stream>>>(
      state, gw1, gb1, gln_g, gln_b, gw2, gb2, temp,
      e1_w, e1_b, ln1_g, ln1_b, e2_w, e2_b, ln2_g, ln2_b, e3_w, e3_b,
      out_policy, out_blend);
}

// Round 5
// 6074.141 us; speedup vs baseline: 1.0158x; 1.0158x over previous
//
#include <hip/hip_runtime.h>

// ---------------------------------------------------------------------------
// Fused MANN. R4 = R2 resubmit (R2/R3 benches failed on GPU acquisition).
//  - __launch_bounds__(256) only (no min-waves arg). R1's (256,3) drove the
//    allocator to 84 VGPR -> scratch spill (WRITE_SIZE 3.5->163 MB, dur 2x).
//    Occupancy is limited to 3 blocks/CU by LDS (50.7 KB) instead.
//  - Explicit (ic,k)-phase double-buffered weight prefetch in expert_layer:
//    8 float4 loads for phase p+1 issued before the 64 FMAs of phase p.
// ---------------------------------------------------------------------------

constexpr int B_TOT = 131072;
constexpr int IN    = 256;
constexpr int HID   = 128;
constexpr int GH    = 64;
constexpr int KEXP  = 4;
constexpr int NA    = 3;
constexpr int ROWS  = 32;        // rows per block
constexpr int RPT   = 2;         // rows per thread
constexpr int XS    = IN + 4;    // padded stride for x tile (floats)
constexpr int YS    = HID + 4;   // padded stride for hidden tiles
constexpr int HS    = GH + 4;    // padded stride for gating hidden
constexpr float EPS = 1e-5f;

__device__ __forceinline__ void fma4(float& a, const float4 x, const float4 w) {
  a = fmaf(x.x, w.x, fmaf(x.y, w.y, fmaf(x.z, w.z, fmaf(x.w, w.w, a))));
}

// Blended expert layer: sout[r][o] = relu(LN_o( sum_k bl[r][k] *
//   (dot(sin[r], W[k][o]) + eb[k][o]) ))
template<int L, int SIN>
__device__ __forceinline__ void expert_layer(
    const float* sin_, float* sout,
    const float bl[RPT][4], int r0, int og,
    const float* __restrict__ W, const float* __restrict__ eb,
    const float* __restrict__ lg, const float* __restrict__ lb)
{
  constexpr int IC = L / 4;      // float4 steps along input dim
  float acc[RPT][8];
#pragma unroll
  for (int r = 0; r < RPT; ++r)
#pragma unroll
    for (int j = 0; j < 8; ++j) acc[r][j] = 0.f;

  // per-k weight base pointers (float4 granularity); row j is +IC apart
  const float4* wp[KEXP];
#pragma unroll
  for (int k = 0; k < KEXP; ++k)
    wp[k] = reinterpret_cast<const float4*>(W) + ((size_t)(k * HID + og * 8)) * IC;

  float4 wb[2][8];
  // prefetch phase 0 (ic=0, k=0)
#pragma unroll
  for (int j = 0; j < 8; ++j) wb[0][j] = wp[0][j * IC];

  int buf = 0;
  for (int ic = 0; ic < IC; ++ic) {
    float4 xv[RPT];
#pragma unroll
    for (int r = 0; r < RPT; ++r)
      xv[r] = *(const float4*)&sin_[(r0 + r) * SIN + ic * 4];

#pragma unroll
    for (int k = 0; k < KEXP; ++k) {
      // prefetch next phase into wb[buf^1] (wave-uniform branch)
      {
        int nk = k + 1, nic = ic;
        if (nk == KEXP) { nk = 0; ++nic; }
        if (nic < IC) {
#pragma unroll
          for (int j = 0; j < 8; ++j) wb[buf ^ 1][j] = wp[nk][j * IC + nic];
        }
      }
      // compute with wb[buf]
      float4 tx[RPT];
#pragma unroll
      for (int r = 0; r < RPT; ++r) {
        const float s = bl[r][k];
        tx[r].x = s * xv[r].x; tx[r].y = s * xv[r].y;
        tx[r].z = s * xv[r].z; tx[r].w = s * xv[r].w;
      }
#pragma unroll
      for (int j = 0; j < 8; ++j)
#pragma unroll
        for (int r = 0; r < RPT; ++r)
          fma4(acc[r][j], tx[r], wb[buf][j]);
      buf ^= 1;
    }
  }

  // blended bias
#pragma unroll
  for (int j = 0; j < 8; ++j) {
    const int o = og * 8 + j;
#pragma unroll
    for (int k = 0; k < KEXP; ++k) {
      const float ebv = eb[k * HID + o];
#pragma unroll
      for (int r = 0; r < RPT; ++r) acc[r][j] += bl[r][k] * ebv;
    }
  }

  // LayerNorm over 128 outs (8 per thread x 16 og-lanes) + relu + store
#pragma unroll
  for (int r = 0; r < RPT; ++r) {
    float s = 0.f;
#pragma unroll
    for (int j = 0; j < 8; ++j) s += acc[r][j];
#pragma unroll
    for (int m = 1; m < 16; m <<= 1) s += __shfl_xor(s, m, 64);
    const float mu = s * (1.0f / 128.0f);
    float q = 0.f;
#pragma unroll
    for (int j = 0; j < 8; ++j) { const float d = acc[r][j] - mu; q += d * d; }
#pragma unroll
    for (int m = 1; m < 16; m <<= 1) q += __shfl_xor(q, m, 64);
    const float rstd = rsqrtf(q * (1.0f / 128.0f) + EPS);
#pragma unroll
    for (int j = 0; j < 8; ++j) {
      const int o = og * 8 + j;
      const float y = (acc[r][j] - mu) * rstd * lg[o] + lb[o];
      sout[(r0 + r) * YS + o] = fmaxf(y, 0.f);
    }
  }
}

__global__ __launch_bounds__(256) void mann_fused(
    const float* __restrict__ state,
    const float* __restrict__ gw1, const float* __restrict__ gb1,
    const float* __restrict__ gln_g, const float* __restrict__ gln_b,
    const float* __restrict__ gw2, const float* __restrict__ gb2,
    const float* __restrict__ temperature,
    const float* __restrict__ e1_w, const float* __restrict__ e1_b,
    const float* __restrict__ ln1_g, const float* __restrict__ ln1_b,
    const float* __restrict__ e2_w, const float* __restrict__ e2_b,
    const float* __restrict__ ln2_g, const float* __restrict__ ln2_b,
    const float* __restrict__ e3_w, const float* __restrict__ e3_b,
    float* __restrict__ out_policy, float* __restrict__ out_blend)
{
  // LDS: x tile (32x260) | a tile (32x132, doubles as gating-h 32x68) | blend
  // b tile overlays the x tile (x is dead after layer 1). Total 50688 B.
  __shared__ float smem[ROWS * XS + ROWS * YS + ROWS * KEXP];
  float* sx  = smem;
  float* sa  = smem + ROWS * XS;
  float* sb  = smem;                       // overlay: valid after layer-1 sync
  float* sh  = sa;                         // gating hidden, stride HS
  float* sbl = smem + ROWS * XS + ROWS * YS;

  const int tid = threadIdx.x;
  const int rowbase = blockIdx.x * ROWS;
  const int rowg = tid >> 4, og = tid & 15;
  const int r0 = rowg * RPT;

  // ---- Phase A: stage 32x256 fp32 x-tile (fully coalesced float4) ----
  {
    const float4* gsrc =
        reinterpret_cast<const float4*>(state + (size_t)rowbase * IN);
#pragma unroll
    for (int it = 0; it < 8; ++it) {
      const int fi = tid + it * 256;        // 0..2047
      const int row = fi >> 6, c4 = fi & 63;
      const float4 v = gsrc[fi];
      *reinterpret_cast<float4*>(&sx[row * XS + c4 * 4]) = v;
    }
  }
  __syncthreads();

  // ---- Phase B: gating hidden (256 -> 64) + LN + relu ----
  {
    float acc[RPT][4];
#pragma unroll
    for (int r = 0; r < RPT; ++r)
#pragma unroll
      for (int j = 0; j < 4; ++j) acc[r][j] = 0.f;

    for (int ic = 0; ic < IN / 4; ++ic) {
      float4 xv[RPT];
#pragma unroll
      for (int r = 0; r < RPT; ++r)
        xv[r] = *(const float4*)&sx[(r0 + r) * XS + ic * 4];
#pragma unroll
      for (int j = 0; j < 4; ++j) {
        const float4 wv = *(const float4*)&gw1[(og * 4 + j) * IN + ic * 4];
#pragma unroll
        for (int r = 0; r < RPT; ++r)
          fma4(acc[r][j], xv[r], wv);
      }
    }

    // +bias, LN over 64, relu, store h
#pragma unroll
    for (int r = 0; r < RPT; ++r) {
      float v[4];
      float s = 0.f;
#pragma unroll
      for (int j = 0; j < 4; ++j) {
        v[j] = acc[r][j] + gb1[og * 4 + j];
        s += v[j];
      }
#pragma unroll
      for (int m = 1; m < 16; m <<= 1) s += __shfl_xor(s, m, 64);
      const float mu = s * (1.0f / 64.0f);
      float q = 0.f;
#pragma unroll
      for (int j = 0; j < 4; ++j) { const float d = v[j] - mu; q += d * d; }
#pragma unroll
      for (int m = 1; m < 16; m <<= 1) q += __shfl_xor(q, m, 64);
      const float rstd = rsqrtf(q * (1.0f / 64.0f) + EPS);
#pragma unroll
      for (int j = 0; j < 4; ++j) {
        const int o = og * 4 + j;
        const float hh = (v[j] - mu) * rstd * gln_g[o] + gln_b[o];
        sh[(r0 + r) * HS + o] = fmaxf(hh, 0.f);
      }
    }
  }
  __syncthreads();

  // ---- Phase B2: logits + softmax -> blend (128 threads: 32 rows x 4 k) ----
  if (tid < ROWS * KEXP) {
    const int row = tid >> 2, k = tid & 3;
    float s = 0.f;
#pragma unroll
    for (int i = 0; i < GH; ++i) s += sh[row * HS + i] * gw2[k * GH + i];
    s += gb2[k];
    float t = temperature[0];
    t = fminf(fmaxf(t, 0.1f), 2.0f);
    s = s / t;
    float m = s;
    m = fmaxf(m, __shfl_xor(m, 1, 64));
    m = fmaxf(m, __shfl_xor(m, 2, 64));
    const float e = expf(s - m);
    float sum = e;
    sum += __shfl_xor(sum, 1, 64);
    sum += __shfl_xor(sum, 2, 64);
    const float bl = e / sum;
    sbl[row * 4 + k] = bl;
    out_blend[(size_t)(rowbase + row) * 4 + k] = bl;
  }
  __syncthreads();

  // blends for my rows into registers
  float bl[RPT][4];
#pragma unroll
  for (int r = 0; r < RPT; ++r)
#pragma unroll
    for (int k = 0; k < 4; ++k) bl[r][k] = sbl[(r0 + r) * 4 + k];

  // ---- Phase C: expert layer 1 (256 -> 128), writes sa ----
  expert_layer<IN, XS>(sx, sa, bl, r0, og, e1_w, e1_b, ln1_g, ln1_b);
  __syncthreads();

  // ---- Phase D: expert layer 2 (128 -> 128), writes sb (overlays sx) ----
  expert_layer<HID, YS>(sa, sb, bl, r0, og, e2_w, e2_b, ln2_g, ln2_b);
  __syncthreads();

  // ---- Phase E: expert layer 3 (128 -> 3) + blend reduce ----
  if (tid < ROWS * KEXP) {
    const int row = tid >> 2, k = tid & 3;
    float p[NA] = {0.f, 0.f, 0.f};
#pragma unroll
    for (int ic = 0; ic < HID / 4; ++ic) {
      const float4 xv = *(const float4*)&sb[row * YS + ic * 4];
#pragma unroll
      for (int a = 0; a < NA; ++a) {
        const float4 wv =
            *(const float4*)&e3_w[((size_t)(k * NA + a)) * HID + ic * 4];
        fma4(p[a], xv, wv);
      }
    }
    const float blk = sbl[row * 4 + k];
#pragma unroll
    for (int a = 0; a < NA; ++a) p[a] = blk * (p[a] + e3_b[k * NA + a]);
#pragma unroll
    for (int a = 0; a < NA; ++a) {
      p[a] += __shfl_xor(p[a], 1, 64);
      p[a] += __shfl_xor(p[a], 2, 64);
    }
    if (k == 0) {
      const size_t o = (size_t)(rowbase + row) * NA;
      out_policy[o + 0] = p[0];
      out_policy[o + 1] = p[1];
      out_policy[o + 2] = p[2];
    }
  }
}

extern "C" void kernel_launch(void* const* d_in, const int* in_sizes, int n_in,
                              void* d_out, int out_size, void* d_ws, size_t ws_size,
                              hipStream_t stream) {
  const float* state = (const float*)d_in[0];
  const float* gw1   = (const float*)d_in[1];
  const float* gb1   = (const float*)d_in[2];
  const float* gln_g = (const float*)d_in[3];
  const float* gln_b = (const float*)d_in[4];
  const float* gw2   = (const float*)d_in[5];
  const float* gb2   = (const float*)d_in[6];
  const float* temp  = (const float*)d_in[7];
  const float* e1_w  = (const float*)d_in[8];
  const float* e1_b  = (const float*)d_in[9];
  const float* ln1_g = (const float*)d_in[10];
  const float* ln1_b = (const float*)d_in[11];
  const float* e2_w  = (const float*)d_in[12];
  const float* e2_b  = (const float*)d_in[13];
  const float* ln2_g = (const float*)d_in[14];
  const float* ln2_b = (const float*)d_in[15];
  const float* e3_w  = (const float*)d_in[16];
  const float* e3_b  = (const float*)d_in[17];

  float* out_policy = (float*)d_out;                       // [B,3]
  float* out_blend  = (float*)d_out + (size_t)B_TOT * NA;  // [B,4]

  const int grid = B_TOT / ROWS;  // 4096
  mann_fused<<<grid, 256, 0, stream>>>(
      state, gw1, gb1, gln_g, gln_b, gw2, gb2, temp,
      e1_w, e1_b, ln1_g, ln1_b, e2_w, e2_b, ln2_g, ln2_b, e3_w, e3_b,
      out_policy, out_blend);
}

// Round 6
// 573.889 us; speedup vs baseline: 10.7517x; 10.5842x over previous
//
#include <hip/hip_runtime.h>

// ---------------------------------------------------------------------------
// Fused MANN, R5: MFMA split-bf16 rewrite.
// Evidence: R0 (ROWS=64) 3300us vs R1/R4 (ROWS=32) ~6100us regardless of
// spill -> bound by per-block weight streaming (scattered loads), not VALU.
// fp32 VALU path floor ~400us; MFMA bf16 path floor ~84us. Moves:
//  - prep kernel: weights -> frag-major bf16 hi/lo in d_ws (per-wave weight
//    load = contiguous 1KB dwordx4, fully coalesced).
//  - fp32 emulated via 3-term split-bf16: Ah*Wh + Al*Wh + Ah*Wl.
//  - experts sequential, blend-fold in fp32 epilogue (blend never rounded).
//  - LN via in-register shfl partials + cross-wave LDS stats.
//  - x / activations in LDS bf16 hi+lo, padded or XOR-swizzled strides.
//  - LDS 72.2KB -> 2 blocks/CU. __launch_bounds__(256) only (R1 lesson).
// ---------------------------------------------------------------------------

typedef __attribute__((ext_vector_type(8))) short short8;
typedef __attribute__((ext_vector_type(4))) float f32x4;

constexpr int B_TOT = 131072;
constexpr int IN    = 256;
constexpr int HID   = 128;
constexpr int GH    = 64;
constexpr int KEXP  = 4;
constexpr int NA    = 3;
constexpr int ROWS  = 64;
constexpr int XS    = 264;      // bf16 stride of x tiles (528B: 16B-aligned, 2-way banks)
constexpr int BS    = 132;      // f32 stride of layer3-input tile
constexpr float EPS = 1e-5f;

// ws layout (ushort element offsets); frag-major: [tile][kc][lane][8]
constexpr int O_G1H = 0;        // 4gt*8kc*64*8   = 16384
constexpr int O_G1L = 16384;
constexpr int O_E1H = 32768;    // 4ke*8ot*8kc*64*8 = 131072
constexpr int O_E1L = 163840;
constexpr int O_E2H = 294912;   // 4ke*8ot*4kc*64*8 = 65536
constexpr int O_E2L = 360448;   // total 425984 ushorts = 832KB

__device__ __forceinline__ unsigned short bf16h(float f) {
  unsigned int u = __float_as_uint(f);
  return (unsigned short)((u + 0x7FFFu + ((u >> 16) & 1u)) >> 16);  // RNE
}
__device__ __forceinline__ float bf16f(unsigned short h) {
  return __uint_as_float(((unsigned int)h) << 16);
}

// ---- prep: fp32 weights -> frag-major bf16 hi/lo in ws -------------------
__global__ __launch_bounds__(256) void prep_w(
    const float* __restrict__ gw1, const float* __restrict__ e1w,
    const float* __restrict__ e2w, unsigned short* __restrict__ ws)
{
  const int NT = 16384 + 131072 + 65536;
  for (int d = blockIdx.x * 256 + threadIdx.x; d < NT; d += gridDim.x * 256) {
    float v; int dst, lo_off;
    if (d < 16384) {
      int d2 = d; int j = d2 & 7, lane = (d2 >> 3) & 63, kc = (d2 >> 9) & 7, gt = d2 >> 12;
      int o = gt * 16 + (lane & 15), k = kc * 32 + (lane >> 4) * 8 + j;
      v = gw1[o * IN + k]; dst = O_G1H + d2; lo_off = 16384;
    } else if (d < 147456) {
      int d2 = d - 16384; int j = d2 & 7, lane = (d2 >> 3) & 63, kc = (d2 >> 9) & 7,
          ot = (d2 >> 12) & 7, ke = d2 >> 15;
      int o = ot * 16 + (lane & 15), k = kc * 32 + (lane >> 4) * 8 + j;
      v = e1w[ke * HID * IN + o * IN + k]; dst = O_E1H + d2; lo_off = 131072;
    } else {
      int d2 = d - 147456; int j = d2 & 7, lane = (d2 >> 3) & 63, kc = (d2 >> 9) & 3,
          ot = (d2 >> 11) & 7, ke = d2 >> 14;
      int o = ot * 16 + (lane & 15), k = kc * 32 + (lane >> 4) * 8 + j;
      v = e2w[ke * HID * HID + o * HID + k]; dst = O_E2H + d2; lo_off = 65536;
    }
    unsigned short h = bf16h(v);
    ws[dst] = h;
    ws[dst + lo_off] = bf16h(v - bf16f(h));
  }
}

#define MFMA(a, b, c) __builtin_amdgcn_mfma_f32_16x16x32_bf16((a), (b), (c), 0, 0, 0)

__global__ __launch_bounds__(256) void mann_mfma(
    const float* __restrict__ state,
    const float* __restrict__ gb1,
    const float* __restrict__ gln_g, const float* __restrict__ gln_b,
    const float* __restrict__ gw2, const float* __restrict__ gb2,
    const float* __restrict__ temperature,
    const float* __restrict__ e1_b,
    const float* __restrict__ ln1_g, const float* __restrict__ ln1_b,
    const float* __restrict__ e2_b,
    const float* __restrict__ ln2_g, const float* __restrict__ ln2_b,
    const float* __restrict__ e3_w, const float* __restrict__ e3_b,
    const unsigned short* __restrict__ wf,
    float* __restrict__ out_policy, float* __restrict__ out_blend)
{
  __shared__ __align__(16) unsigned char smem[72192];
  unsigned short* xh = (unsigned short*)smem;              // [64][264]
  unsigned short* xl = (unsigned short*)(smem + 33792);    // [64][264]
  unsigned short* ah = (unsigned short*)(smem + 33792);    // overlay: [64][128] swizzled
  unsigned short* al = (unsigned short*)(smem + 50176);    // overlay: [64][128] swizzled
  float* bt    = (float*)smem;                             // overlay: [64][132]
  float* ps    = (float*)(smem + 67584);                   // [64][2 oh][2]
  float* stats = (float*)(smem + 68608);                   // [64][2]
  float* lp    = (float*)(smem + 69120);                   // [64][2 oh][4]
  float* sbl   = (float*)(smem + 71168);                   // [64][4]

  const int tid = threadIdx.x;
  const int lane = tid & 63, wv = tid >> 6;
  const int l15 = lane & 15, l4 = lane >> 4;
  const int rh = wv >> 1, oh = wv & 1;   // row-half, out-half
  const int rowbase = blockIdx.x * ROWS;

  // ---- Phase A: stage x as bf16 hi/lo (coalesced float4 reads) ----
  {
    const float4* gsrc = (const float4*)(state + (size_t)rowbase * IN);
#pragma unroll
    for (int it = 0; it < 16; ++it) {
      int fi = tid + it * 256;
      int row = fi >> 6, c4 = fi & 63;
      float4 v = gsrc[fi];
      int base = row * XS + c4 * 4;
      float vv[4] = {v.x, v.y, v.z, v.w};
#pragma unroll
      for (int e = 0; e < 4; ++e) {
        unsigned short h = bf16h(vv[e]);
        xh[base + e] = h;
        xl[base + e] = bf16h(vv[e] - bf16f(h));
      }
    }
  }
  __syncthreads();

  // ---- Gating: MFMA (64 outs), LN, logits, softmax ----
  {
    f32x4 z = {0.f, 0.f, 0.f, 0.f};
    f32x4 g[2][2] = {{z, z}, {z, z}};
#pragma unroll
    for (int kc = 0; kc < 8; ++kc) {
      short8 wh[2], wl[2];
#pragma unroll
      for (int ot = 0; ot < 2; ++ot) {
        int gt = oh * 2 + ot;
        const unsigned short* p = wf + O_G1H + ((gt * 8 + kc) * 64 + lane) * 8;
        wh[ot] = *(const short8*)p;
        wl[ot] = *(const short8*)(p + 16384);
      }
#pragma unroll
      for (int rt = 0; rt < 2; ++rt) {
        int row = rh * 32 + rt * 16 + l15;
        int xo = row * XS + kc * 32 + l4 * 8;
        short8 xhf = *(const short8*)&xh[xo];
        short8 xlf = *(const short8*)&xl[xo];
#pragma unroll
        for (int ot = 0; ot < 2; ++ot) {
          g[rt][ot] = MFMA(xhf, wh[ot], g[rt][ot]);
          g[rt][ot] = MFMA(xlf, wh[ot], g[rt][ot]);
          g[rt][ot] = MFMA(xhf, wl[ot], g[rt][ot]);
        }
      }
    }
    // + gb1 (col = lane&15 per D-layout), then row stats over 64 cols
#pragma unroll
    for (int ot = 0; ot < 2; ++ot) {
      float bv = gb1[oh * 32 + ot * 16 + l15];
#pragma unroll
      for (int rt = 0; rt < 2; ++rt)
#pragma unroll
        for (int r = 0; r < 4; ++r) g[rt][ot][r] += bv;
    }
#pragma unroll
    for (int rt = 0; rt < 2; ++rt)
#pragma unroll
      for (int r = 0; r < 4; ++r) {
        float sv = g[rt][0][r] + g[rt][1][r];
        float qv = g[rt][0][r] * g[rt][0][r] + g[rt][1][r] * g[rt][1][r];
#pragma unroll
        for (int m = 1; m < 16; m <<= 1) { sv += __shfl_xor(sv, m, 64); qv += __shfl_xor(qv, m, 64); }
        if (l15 == 0) {
          int row = rh * 32 + rt * 16 + l4 * 4 + r;
          ps[row * 4 + oh * 2 + 0] = sv;
          ps[row * 4 + oh * 2 + 1] = qv;
        }
      }
    __syncthreads();
    if (tid < 64) {
      float s = ps[tid * 4] + ps[tid * 4 + 2];
      float q = ps[tid * 4 + 1] + ps[tid * 4 + 3];
      float mu = s * (1.f / GH);
      float var = q * (1.f / GH) - mu * mu;
      stats[tid * 2] = mu; stats[tid * 2 + 1] = rsqrtf(var + EPS);
    }
    __syncthreads();
    float gg[2], gbb[2], gw2v[2][4];
#pragma unroll
    for (int ot = 0; ot < 2; ++ot) {
      int c = oh * 32 + ot * 16 + l15;
      gg[ot] = gln_g[c]; gbb[ot] = gln_b[c];
#pragma unroll
      for (int kk = 0; kk < 4; ++kk) gw2v[ot][kk] = gw2[kk * GH + c];
    }
#pragma unroll
    for (int rt = 0; rt < 2; ++rt)
#pragma unroll
      for (int r = 0; r < 4; ++r) {
        int row = rh * 32 + rt * 16 + l4 * 4 + r;
        float mu = stats[row * 2], rstd = stats[row * 2 + 1];
        float h0 = fmaxf((g[rt][0][r] - mu) * rstd * gg[0] + gbb[0], 0.f);
        float h1 = fmaxf((g[rt][1][r] - mu) * rstd * gg[1] + gbb[1], 0.f);
#pragma unroll
        for (int kk = 0; kk < 4; ++kk) {
          float pv = h0 * gw2v[0][kk] + h1 * gw2v[1][kk];
#pragma unroll
          for (int m = 1; m < 16; m <<= 1) pv += __shfl_xor(pv, m, 64);
          if (l15 == 0) lp[row * 8 + oh * 4 + kk] = pv;
        }
      }
    __syncthreads();
  }
  {
    int row = tid >> 2, kk = tid & 3;
    float lg = lp[row * 8 + kk] + lp[row * 8 + 4 + kk] + gb2[kk];
    float t = fminf(fmaxf(temperature[0], 0.1f), 2.0f);
    lg /= t;
    float mx = lg;
    mx = fmaxf(mx, __shfl_xor(mx, 1, 64));
    mx = fmaxf(mx, __shfl_xor(mx, 2, 64));
    float e = expf(lg - mx);
    float su = e;
    su += __shfl_xor(su, 1, 64);
    su += __shfl_xor(su, 2, 64);
    float bl = e / su;
    sbl[row * 4 + kk] = bl;
    out_blend[(size_t)(rowbase + row) * 4 + kk] = bl;
  }
  __syncthreads();

  f32x4 zz = {0.f, 0.f, 0.f, 0.f};
  f32x4 accb[2][4] = {{zz, zz, zz, zz}, {zz, zz, zz, zz}};

  // ---- Layer 1: experts sequential, blend-fold in fp32 ----
#pragma unroll
  for (int ke = 0; ke < KEXP; ++ke) {
    f32x4 t[2][4] = {{zz, zz, zz, zz}, {zz, zz, zz, zz}};
#pragma unroll
    for (int kc = 0; kc < 8; ++kc) {
      short8 wh[4], wl[4];
#pragma unroll
      for (int ot = 0; ot < 4; ++ot) {
        int got = oh * 4 + ot;
        const unsigned short* p = wf + O_E1H + (((ke * 8 + got) * 8 + kc) * 64 + lane) * 8;
        wh[ot] = *(const short8*)p;
        wl[ot] = *(const short8*)(p + 131072);
      }
#pragma unroll
      for (int rt = 0; rt < 2; ++rt) {
        int row = rh * 32 + rt * 16 + l15;
        int xo = row * XS + kc * 32 + l4 * 8;
        short8 xhf = *(const short8*)&xh[xo];
        short8 xlf = *(const short8*)&xl[xo];
#pragma unroll
        for (int ot = 0; ot < 4; ++ot) {
          t[rt][ot] = MFMA(xhf, wh[ot], t[rt][ot]);
          t[rt][ot] = MFMA(xlf, wh[ot], t[rt][ot]);
          t[rt][ot] = MFMA(xhf, wl[ot], t[rt][ot]);
        }
      }
    }
#pragma unroll
    for (int ot = 0; ot < 4; ++ot) {
      float bv = e1_b[ke * HID + oh * 64 + ot * 16 + l15];
#pragma unroll
      for (int rt = 0; rt < 2; ++rt)
#pragma unroll
        for (int r = 0; r < 4; ++r) {
          int row = rh * 32 + rt * 16 + l4 * 4 + r;
          float blv = sbl[row * 4 + ke];
          accb[rt][ot][r] += blv * (t[rt][ot][r] + bv);
        }
    }
  }
  // L1 LN (distributed stats) -> a tiles (bf16 hi/lo, granule-XOR swizzle)
#pragma unroll
  for (int rt = 0; rt < 2; ++rt)
#pragma unroll
    for (int r = 0; r < 4; ++r) {
      float sv = 0.f, qv = 0.f;
#pragma unroll
      for (int ot = 0; ot < 4; ++ot) { float v = accb[rt][ot][r]; sv += v; qv += v * v; }
#pragma unroll
      for (int m = 1; m < 16; m <<= 1) { sv += __shfl_xor(sv, m, 64); qv += __shfl_xor(qv, m, 64); }
      if (l15 == 0) {
        int row = rh * 32 + rt * 16 + l4 * 4 + r;
        ps[row * 4 + oh * 2 + 0] = sv;
        ps[row * 4 + oh * 2 + 1] = qv;
      }
    }
  __syncthreads();
  if (tid < 64) {
    float s = ps[tid * 4] + ps[tid * 4 + 2];
    float q = ps[tid * 4 + 1] + ps[tid * 4 + 3];
    float mu = s * (1.f / HID), var = q * (1.f / HID) - mu * mu;
    stats[tid * 2] = mu; stats[tid * 2 + 1] = rsqrtf(var + EPS);
  }
  __syncthreads();
  {
    float lg_[4], lb_[4];
#pragma unroll
    for (int ot = 0; ot < 4; ++ot) {
      int c = oh * 64 + ot * 16 + l15;
      lg_[ot] = ln1_g[c]; lb_[ot] = ln1_b[c];
    }
#pragma unroll
    for (int rt = 0; rt < 2; ++rt)
#pragma unroll
      for (int r = 0; r < 4; ++r) {
        int row = rh * 32 + rt * 16 + l4 * 4 + r;
        float mu = stats[row * 2], rstd = stats[row * 2 + 1];
#pragma unroll
        for (int ot = 0; ot < 4; ++ot) {
          int c = oh * 64 + ot * 16 + l15;
          float y = fmaxf((accb[rt][ot][r] - mu) * rstd * lg_[ot] + lb_[ot], 0.f);
          unsigned short h = bf16h(y);
          int idx = row * HID + (((c >> 3) ^ (row & 7)) << 3) + (c & 7);
          ah[idx] = h; al[idx] = bf16h(y - bf16f(h));
        }
      }
  }
  __syncthreads();

  // ---- Layer 2 (inner 128 per expert, frags from swizzled a tiles) ----
#pragma unroll
  for (int rt = 0; rt < 2; ++rt)
#pragma unroll
    for (int ot = 0; ot < 4; ++ot) accb[rt][ot] = zz;
#pragma unroll
  for (int ke = 0; ke < KEXP; ++ke) {
    f32x4 t[2][4] = {{zz, zz, zz, zz}, {zz, zz, zz, zz}};
#pragma unroll
    for (int kc = 0; kc < 4; ++kc) {
      short8 wh[4], wl[4];
#pragma unroll
      for (int ot = 0; ot < 4; ++ot) {
        int got = oh * 4 + ot;
        const unsigned short* p = wf + O_E2H + (((ke * 8 + got) * 4 + kc) * 64 + lane) * 8;
        wh[ot] = *(const short8*)p;
        wl[ot] = *(const short8*)(p + 65536);
      }
#pragma unroll
      for (int rt = 0; rt < 2; ++rt) {
        int row = rh * 32 + rt * 16 + l15;
        int gidx = (kc * 4 + l4) ^ (row & 7);
        int idx = row * HID + gidx * 8;
        short8 xhf = *(const short8*)&ah[idx];
        short8 xlf = *(const short8*)&al[idx];
#pragma unroll
        for (int ot = 0; ot < 4; ++ot) {
          t[rt][ot] = MFMA(xhf, wh[ot], t[rt][ot]);
          t[rt][ot] = MFMA(xlf, wh[ot], t[rt][ot]);
          t[rt][ot] = MFMA(xhf, wl[ot], t[rt][ot]);
        }
      }
    }
#pragma unroll
    for (int ot = 0; ot < 4; ++ot) {
      float bv = e2_b[ke * HID + oh * 64 + ot * 16 + l15];
#pragma unroll
      for (int rt = 0; rt < 2; ++rt)
#pragma unroll
        for (int r = 0; r < 4; ++r) {
          int row = rh * 32 + rt * 16 + l4 * 4 + r;
          float blv = sbl[row * 4 + ke];
          accb[rt][ot][r] += blv * (t[rt][ot][r] + bv);
        }
    }
  }
  // L2 LN -> bt (fp32)
#pragma unroll
  for (int rt = 0; rt < 2; ++rt)
#pragma unroll
    for (int r = 0; r < 4; ++r) {
      float sv = 0.f, qv = 0.f;
#pragma unroll
      for (int ot = 0; ot < 4; ++ot) { float v = accb[rt][ot][r]; sv += v; qv += v * v; }
#pragma unroll
      for (int m = 1; m < 16; m <<= 1) { sv += __shfl_xor(sv, m, 64); qv += __shfl_xor(qv, m, 64); }
      if (l15 == 0) {
        int row = rh * 32 + rt * 16 + l4 * 4 + r;
        ps[row * 4 + oh * 2 + 0] = sv;
        ps[row * 4 + oh * 2 + 1] = qv;
      }
    }
  __syncthreads();
  if (tid < 64) {
    float s = ps[tid * 4] + ps[tid * 4 + 2];
    float q = ps[tid * 4 + 1] + ps[tid * 4 + 3];
    float mu = s * (1.f / HID), var = q * (1.f / HID) - mu * mu;
    stats[tid * 2] = mu; stats[tid * 2 + 1] = rsqrtf(var + EPS);
  }
  __syncthreads();
  {
    float lg_[4], lb_[4];
#pragma unroll
    for (int ot = 0; ot < 4; ++ot) {
      int c = oh * 64 + ot * 16 + l15;
      lg_[ot] = ln2_g[c]; lb_[ot] = ln2_b[c];
    }
#pragma unroll
    for (int rt = 0; rt < 2; ++rt)
#pragma unroll
      for (int r = 0; r < 4; ++r) {
        int row = rh * 32 + rt * 16 + l4 * 4 + r;
        float mu = stats[row * 2], rstd = stats[row * 2 + 1];
#pragma unroll
        for (int ot = 0; ot < 4; ++ot) {
          int c = oh * 64 + ot * 16 + l15;
          float y = fmaxf((accb[rt][ot][r] - mu) * rstd * lg_[ot] + lb_[ot], 0.f);
          bt[row * BS + c] = y;
        }
      }
  }
  __syncthreads();

  // ---- Layer 3 (128 -> 3) + blend reduce, VALU ----
  {
    int row = tid >> 2, kk = tid & 3;
    float p[NA] = {0.f, 0.f, 0.f};
#pragma unroll
    for (int ic = 0; ic < HID / 4; ++ic) {
      float4 xv = *(const float4*)&bt[row * BS + ic * 4];
#pragma unroll
      for (int a = 0; a < NA; ++a) {
        float4 wv = *(const float4*)&e3_w[(size_t)(kk * NA + a) * HID + ic * 4];
        p[a] = fmaf(xv.x, wv.x, fmaf(xv.y, wv.y, fmaf(xv.z, wv.z, fmaf(xv.w, wv.w, p[a]))));
      }
    }
    float blk = sbl[row * 4 + kk];
#pragma unroll
    for (int a = 0; a < NA; ++a) p[a] = blk * (p[a] + e3_b[kk * NA + a]);
#pragma unroll
    for (int a = 0; a < NA; ++a) {
      p[a] += __shfl_xor(p[a], 1, 64);
      p[a] += __shfl_xor(p[a], 2, 64);
    }
    if (kk == 0) {
      size_t o = (size_t)(rowbase + row) * NA;
      out_policy[o + 0] = p[0];
      out_policy[o + 1] = p[1];
      out_policy[o + 2] = p[2];
    }
  }
}

extern "C" void kernel_launch(void* const* d_in, const int* in_sizes, int n_in,
                              void* d_out, int out_size, void* d_ws, size_t ws_size,
                              hipStream_t stream) {
  const float* state = (const float*)d_in[0];
  const float* gw1   = (const float*)d_in[1];
  const float* gb1   = (const float*)d_in[2];
  const float* gln_g = (const float*)d_in[3];
  const float* gln_b = (const float*)d_in[4];
  const float* gw2   = (const float*)d_in[5];
  const float* gb2   = (const float*)d_in[6];
  const float* temp  = (const float*)d_in[7];
  const float* e1_w  = (const float*)d_in[8];
  const float* e1_b  = (const float*)d_in[9];
  const float* ln1_g = (const float*)d_in[10];
  const float* ln1_b = (const float*)d_in[11];
  const float* e2_w  = (const float*)d_in[12];
  const float* e2_b  = (const float*)d_in[13];
  const float* ln2_g = (const float*)d_in[14];
  const float* ln2_b = (const float*)d_in[15];
  const float* e3_w  = (const float*)d_in[16];
  const float* e3_b  = (const float*)d_in[17];

  unsigned short* wf = (unsigned short*)d_ws;
  float* out_policy = (float*)d_out;                       // [B,3]
  float* out_blend  = (float*)d_out + (size_t)B_TOT * NA;  // [B,4]

  prep_w<<<832, 256, 0, stream>>>(gw1, e1_w, e2_w, wf);
  mann_mfma<<<B_TOT / ROWS, 256, 0, stream>>>(
      state, gb1, gln_g, gln_b, gw2, gb2, temp,
      e1_b, ln1_g, ln1_b, e2_b, ln2_g, ln2_b, e3_w, e3_b,
      wf, out_policy, out_blend);
}